// Round 8
// baseline (203.702 us; speedup 1.0000x reference)
//
#include <hip/hip_runtime.h>

typedef __bf16 bf16x8 __attribute__((ext_vector_type(8)));
typedef float  f32x4  __attribute__((ext_vector_type(4)));

#define MFMA_BF16(a, b, c) __builtin_amdgcn_mfma_f32_16x16x32_bf16((a), (b), (c), 0, 0, 0)
#define NEG_INF (-1e30f)
// softmax scale folded with log2(e): exp(s*0.125) == exp2(s*0.125*1.442695)
#define SCL 0.18033688f

__device__ __forceinline__ void gld16(const void* g, void* l) {
  __builtin_amdgcn_global_load_lds(
      (const __attribute__((address_space(1))) void*)g,
      (__attribute__((address_space(3))) void*)l, 16, 0, 0);
}

// ---------------------------------------------------------------------------
// Cast fp32 -> bf16, 8 elems/thread.
// ---------------------------------------------------------------------------
__global__ void cast_f32_bf16(const float* __restrict__ in,
                              __bf16* __restrict__ out, int n) {
  int i = (blockIdx.x * 256 + threadIdx.x) * 8;
  if (i >= n) return;
  float4 a = *(const float4*)&in[i];
  float4 b = *(const float4*)&in[i + 4];
  bf16x8 v;
  v[0] = (__bf16)a.x; v[1] = (__bf16)a.y; v[2] = (__bf16)a.z; v[3] = (__bf16)a.w;
  v[4] = (__bf16)b.x; v[5] = (__bf16)b.y; v[6] = (__bf16)b.z; v[7] = (__bf16)b.w;
  *(bf16x8*)&out[i] = v;
}

// ---------------------------------------------------------------------------
// Transpose: in [R][C] fp32 -> out [C][R] bf16. 32x32 tiles, 256 threads.
// ---------------------------------------------------------------------------
__global__ void transpose_f32_bf16(const float* __restrict__ in,
                                   __bf16* __restrict__ out, int R, int C) {
  __shared__ float t[32][33];
  int tx = threadIdx.x & 31, ty = threadIdx.x >> 5;  // 32 x 8
  int x = blockIdx.x * 32 + tx;
  int y0 = blockIdx.y * 32 + ty;
#pragma unroll
  for (int i = 0; i < 4; ++i)
    t[ty + 8 * i][tx] = in[(size_t)(y0 + 8 * i) * C + x];
  __syncthreads();
  int x2 = blockIdx.y * 32 + tx;
#pragma unroll
  for (int i = 0; i < 4; ++i)
    out[(size_t)(blockIdx.x * 32 + ty + 8 * i) * R + x2] = (__bf16)t[tx][ty + 8 * i];
}

// ---------------------------------------------------------------------------
// GEMM: C[M][N] = A[M][K]*Bt[N][K]^T + bias[N]. A,Bt bf16, fp32 accum.
// m97 structure + XOR-swizzled LDS: storage chunk (row r, slot s) holds
// global k-chunk s^(r&7) (permuted at gld16-source, lane-linear LDS dest).
// Fragment reads hit slot cc^(l16&7) -> per-phase conflict-free ds_read_b128.
// ---------------------------------------------------------------------------
#define BN 128
#define BK 64

template <int BMT, typename TC>
__global__ __launch_bounds__(256) void gemm_bt_bias(
    const __bf16* __restrict__ A, const __bf16* __restrict__ Bt,
    const float* __restrict__ bias, TC* __restrict__ Cmat,
    int M, int N, int K) {
  constexpr int NI = BMT / 32;  // A chunks per thread; MFMA row-tiles per wave
  __shared__ __align__(16) __bf16 As[BMT * BK];
  __shared__ __align__(16) __bf16 Bs[BN * BK];
  int tid = threadIdx.x;
  int wave = tid >> 6, lane = tid & 63;
  int l16 = lane & 15, quad = lane >> 4;
  int wm = wave >> 1, wn = wave & 1;
  int m0 = blockIdx.y * BMT, n0 = blockIdx.x * BN;

  f32x4 acc[NI][4];
#pragma unroll
  for (int i = 0; i < NI; ++i)
#pragma unroll
    for (int j = 0; j < 4; ++j) acc[i][j] = (f32x4){0.f, 0.f, 0.f, 0.f};

  int row = tid >> 3;                                // 0..31 (+32*i)
  // swizzled source column: slot (tid&7) of row r fetches chunk (tid&7)^(r&7)
  int kc = ((tid & 7) ^ ((tid >> 3) & 7)) * 8;       // i*32 doesn't change r&7
  // fragment-read xor key (elements): chunk cc -> slot cc^(l16&7)
  int xr = (l16 & 7) * 8;

  for (int k0 = 0; k0 < K; k0 += BK) {
#pragma unroll
    for (int i = 0; i < NI; ++i)
      gld16(&A[(size_t)(m0 + row + i * 32) * K + k0 + kc],
            (char*)As + (i * 256 + wave * 64) * 16);
#pragma unroll
    for (int j = 0; j < 4; ++j)
      gld16(&Bt[(size_t)(n0 + row + j * 32) * K + k0 + kc],
            (char*)Bs + (j * 256 + wave * 64) * 16);
    __syncthreads();
#pragma unroll
    for (int ks = 0; ks < 2; ++ks) {
      bf16x8 af[NI], bfr[4];
#pragma unroll
      for (int i = 0; i < NI; ++i)
        af[i] = *(const bf16x8*)&As[(wm * (BMT / 2) + i * 16 + l16) * BK +
                                    ((ks * 32 + quad * 8) ^ xr)];
#pragma unroll
      for (int j = 0; j < 4; ++j)
        bfr[j] = *(const bf16x8*)&Bs[(wn * 64 + j * 16 + l16) * BK +
                                     ((ks * 32 + quad * 8) ^ xr)];
#pragma unroll
      for (int i = 0; i < NI; ++i)
#pragma unroll
        for (int j = 0; j < 4; ++j) acc[i][j] = MFMA_BF16(af[i], bfr[j], acc[i][j]);
    }
    __syncthreads();
  }
  // epilogue: D row = quad*4+r, col = lane&15 within each 16x16 tile
#pragma unroll
  for (int i = 0; i < NI; ++i) {
#pragma unroll
    for (int j = 0; j < 4; ++j) {
      int col = n0 + wn * 64 + j * 16 + l16;
      float bv = bias[col];
#pragma unroll
      for (int r = 0; r < 4; ++r) {
        int rw = m0 + wm * (BMT / 2) + i * 16 + quad * 4 + r;
        Cmat[(size_t)rw * N + col] = (TC)(acc[i][j][r] + bv);
      }
    }
  }
}

// ---------------------------------------------------------------------------
// Causal flash attention, no-max softmax. qkv [B*T][3C] bf16.
// Q-tile = 128 rows/block: 4 waves x 32 q-rows (2 MFMA row-tiles per wave),
// so K/V fragment reads are amortized over 2x the q-rows (the round-7
// bottleneck was LDS-issue from 4-way duplicated fragment reads).
// Grid (32=B*NH, 8=pair): block does qt=pair then qt=15-pair => exactly 34
// kt-tiles per block, 256 blocks = 1/CU, perfectly uniform.
// LDS: stride-72 padded K; V^T with key^d0 swizzle; double-buffered.
// ---------------------------------------------------------------------------
__global__ __launch_bounds__(256) void attn_causal(
    const __bf16* __restrict__ qkv, __bf16* __restrict__ y) {
  __shared__ __align__(16) __bf16 Kb[2][64 * 72];   // [key][dim], pad 72
  __shared__ __align__(16) __bf16 Vb[2][64 * 72];   // [dim][key ^ (dim&56)]
  __shared__ __align__(16) __bf16 Ps[4][32 * 72];   // per-wave P [qrow32][key]
  const int tid = threadIdx.x;
  const int wave = tid >> 6, lane = tid & 63;
  const int l16 = lane & 15, quad = lane >> 4;
  const int bh = blockIdx.x;
  const int b = bh >> 4, h = bh & 15;
  const int RS = 3072;
  const int key0 = tid >> 3;        // 0..31 (+32 for chunk 1)
  const int d0 = (tid & 7) * 8;
  const __bf16* kv0 = qkv + (size_t)(b * 2048) * RS + h * 64 + d0;

#pragma unroll 1
  for (int phase = 0; phase < 2; ++phase) {
    const int qt = phase ? (15 - (int)blockIdx.y) : (int)blockIdx.y;  // 128-row tile
    const int KT = 2 * qt + 2;                                        // 64-key tiles

    // Q fragments for 2 row-tiles: A[m=lane&15][k=quad*8+j]
    bf16x8 qf[2][2];
#pragma unroll
    for (int t = 0; t < 2; ++t) {
      int qrow = b * 2048 + qt * 128 + wave * 32 + t * 16 + l16;
      const __bf16* qbase = qkv + (size_t)qrow * RS + h * 64;
      qf[t][0] = *(const bf16x8*)(qbase + quad * 8);
      qf[t][1] = *(const bf16x8*)(qbase + 32 + quad * 8);
    }

    float l_i[2][4];
    f32x4 o[2][4];
#pragma unroll
    for (int t = 0; t < 2; ++t)
#pragma unroll
      for (int r = 0; r < 4; ++r) l_i[t][r] = 0.f;
#pragma unroll
    for (int t = 0; t < 2; ++t)
#pragma unroll
      for (int j = 0; j < 4; ++j) o[t][j] = (f32x4){0.f, 0.f, 0.f, 0.f};

    // stage tile 0 into buffer 0
    bf16x8 kreg[2], vreg[2];
#pragma unroll
    for (int i = 0; i < 2; ++i) {
      const __bf16* src = kv0 + (size_t)(key0 + 32 * i) * RS;
      kreg[i] = *(const bf16x8*)(src + 1024);
      vreg[i] = *(const bf16x8*)(src + 2048);
    }
#pragma unroll
    for (int i = 0; i < 2; ++i) {
      int key = key0 + 32 * i;
      *(bf16x8*)&Kb[0][key * 72 + d0] = kreg[i];
#pragma unroll
      for (int jj = 0; jj < 8; ++jj)
        Vb[0][(d0 + jj) * 72 + (key ^ d0)] = vreg[i][jj];
    }
    __syncthreads();

    for (int kt = 0; kt < KT; ++kt) {
      const int cur = kt & 1;
      // global prefetch of tile kt+1
      if (kt + 1 < KT) {
#pragma unroll
        for (int i = 0; i < 2; ++i) {
          const __bf16* src = kv0 + (size_t)((kt + 1) * 64 + key0 + 32 * i) * RS;
          kreg[i] = *(const bf16x8*)(src + 1024);
          vreg[i] = *(const bf16x8*)(src + 2048);
        }
      }

      // S = Q K^T for both row-tiles (K frags read once, used twice)
      f32x4 s[2][4];
#pragma unroll
      for (int t = 0; t < 2; ++t)
#pragma unroll
        for (int j = 0; j < 4; ++j) s[t][j] = (f32x4){0.f, 0.f, 0.f, 0.f};
#pragma unroll
      for (int j = 0; j < 4; ++j) {
        bf16x8 kf0 = *(const bf16x8*)&Kb[cur][(j * 16 + l16) * 72 + quad * 8];
        bf16x8 kf1 = *(const bf16x8*)&Kb[cur][(j * 16 + l16) * 72 + 32 + quad * 8];
#pragma unroll
        for (int t = 0; t < 2; ++t) {
          s[t][j] = MFMA_BF16(qf[t][0], kf0, s[t][j]);
          s[t][j] = MFMA_BF16(qf[t][1], kf1, s[t][j]);
        }
      }

      // causal mask on diagonal region (uniform branch)
      if (kt >= 2 * qt) {
        int off = (kt - 2 * qt) * 64;   // key offset within the 128-q block
#pragma unroll
        for (int t = 0; t < 2; ++t) {
          int qg = wave * 32 + t * 16 + quad * 4;  // +r
#pragma unroll
          for (int j = 0; j < 4; ++j)
#pragma unroll
            for (int r = 0; r < 4; ++r)
              if (j * 16 + l16 + off > qg + r) s[t][j][r] = NEG_INF;
        }
      }

      // P = exp2(S*SCL); per-lane l accum; C/D-layout -> LDS (wave-private)
#pragma unroll
      for (int t = 0; t < 2; ++t)
#pragma unroll
        for (int r = 0; r < 4; ++r)
#pragma unroll
          for (int j = 0; j < 4; ++j) {
            float p = __builtin_amdgcn_exp2f(s[t][j][r] * SCL);
            l_i[t][r] += p;
            Ps[wave][(t * 16 + quad * 4 + r) * 72 + j * 16 + l16] = (__bf16)p;
          }

      // O += P V (V frags read once, used for both row-tiles)
#pragma unroll
      for (int ks = 0; ks < 2; ++ks) {
        bf16x8 pf[2];
#pragma unroll
        for (int t = 0; t < 2; ++t)
          pf[t] = *(const bf16x8*)&Ps[wave][(t * 16 + l16) * 72 + ks * 32 + quad * 8];
#pragma unroll
        for (int j = 0; j < 4; ++j) {
          int dim = j * 16 + l16;
          bf16x8 vf = *(const bf16x8*)&Vb[cur][dim * 72 + ((ks * 32 + quad * 8) ^ (dim & 56))];
#pragma unroll
          for (int t = 0; t < 2; ++t) o[t][j] = MFMA_BF16(pf[t], vf, o[t][j]);
        }
      }

      // write prefetched tile kt+1 into the other buffer
      if (kt + 1 < KT) {
#pragma unroll
        for (int i = 0; i < 2; ++i) {
          int key = key0 + 32 * i;
          *(bf16x8*)&Kb[cur ^ 1][key * 72 + d0] = kreg[i];
#pragma unroll
          for (int jj = 0; jj < 8; ++jj)
            Vb[cur ^ 1][(d0 + jj) * 72 + (key ^ d0)] = vreg[i][jj];
        }
      }
      __syncthreads();  // single barrier per tile
    }

    // reduce l across the 16-lane row group, then normalize + store
#pragma unroll
    for (int t = 0; t < 2; ++t) {
      int orow = b * 2048 + qt * 128 + wave * 32 + t * 16 + quad * 4;
#pragma unroll
      for (int r = 0; r < 4; ++r) {
        float l = l_i[t][r];
        l += __shfl_xor(l, 1);
        l += __shfl_xor(l, 2);
        l += __shfl_xor(l, 4);
        l += __shfl_xor(l, 8);
        float inv = 1.f / l;
#pragma unroll
        for (int j = 0; j < 4; ++j)
          y[(size_t)(orow + r) * 1024 + h * 64 + j * 16 + l16] = (__bf16)(o[t][j][r] * inv);
      }
    }
  }
}

// ---------------------------------------------------------------------------
extern "C" void kernel_launch(void* const* d_in, const int* in_sizes, int n_in,
                              void* d_out, int out_size, void* d_ws, size_t ws_size,
                              hipStream_t stream) {
  (void)in_sizes; (void)n_in; (void)out_size; (void)ws_size;
  const float* x      = (const float*)d_in[0];  // [2,2048,1024] fp32
  const float* w_attn = (const float*)d_in[1];  // [1024,3072]
  const float* b_attn = (const float*)d_in[2];  // [3072]
  const float* w_proj = (const float*)d_in[3];  // [1024,1024]
  const float* b_proj = (const float*)d_in[4];  // [1024]
  float* out = (float*)d_out;                   // [2,2048,1024] fp32

  __bf16* wt_attn = (__bf16*)d_ws;                       // [3072][1024]
  __bf16* wt_proj = wt_attn + (size_t)3072 * 1024;       // [1024][1024]
  __bf16* qkv     = wt_proj + (size_t)1024 * 1024;       // [4096][3072]
  __bf16* ybuf    = qkv + (size_t)4096 * 3072;           // [4096][1024]

  // x -> bf16, staged in ybuf (attention overwrites it later; same stream)
  cast_f32_bf16<<<4096 * 1024 / 2048, 256, 0, stream>>>(x, ybuf, 4096 * 1024);

  transpose_f32_bf16<<<dim3(3072 / 32, 1024 / 32), 256, 0, stream>>>(w_attn, wt_attn, 1024, 3072);
  transpose_f32_bf16<<<dim3(1024 / 32, 1024 / 32), 256, 0, stream>>>(w_proj, wt_proj, 1024, 1024);

  // qkv = x @ w_attn + b_attn   (768 blocks, BM=128)
  gemm_bt_bias<128, __bf16><<<dim3(3072 / BN, 4096 / 128), 256, 0, stream>>>(
      ybuf, wt_attn, b_attn, qkv, 4096, 3072, 1024);

  // y = causal_attention(qkv), overwrites ybuf  (256 blocks, q-tile 128)
  attn_causal<<<dim3(2 * 16, 8), 256, 0, stream>>>(qkv, ybuf);

  // out = y @ w_proj + b_proj   (512 blocks, BM=64 for occupancy)
  gemm_bt_bias<64, float><<<dim3(1024 / BN, 4096 / 64), 256, 0, stream>>>(
      ybuf, wt_proj, b_proj, out, 4096, 1024, 1024);
}

// Round 9
// 193.935 us; speedup vs baseline: 1.0504x; 1.0504x over previous
//
#include <hip/hip_runtime.h>

typedef __bf16 bf16x8 __attribute__((ext_vector_type(8)));
typedef float  f32x4  __attribute__((ext_vector_type(4)));

#define MFMA_BF16(a, b, c) __builtin_amdgcn_mfma_f32_16x16x32_bf16((a), (b), (c), 0, 0, 0)
#define NEG_INF (-1e30f)
// softmax scale folded with log2(e): exp(s*0.125) == exp2(s*0.125*1.442695)
#define SCL 0.18033688f

__device__ __forceinline__ void gld16(const void* g, void* l) {
  __builtin_amdgcn_global_load_lds(
      (const __attribute__((address_space(1))) void*)g,
      (__attribute__((address_space(3))) void*)l, 16, 0, 0);
}

// ---------------------------------------------------------------------------
// Cast fp32 -> bf16, 8 elems/thread.
// ---------------------------------------------------------------------------
__global__ void cast_f32_bf16(const float* __restrict__ in,
                              __bf16* __restrict__ out, int n) {
  int i = (blockIdx.x * 256 + threadIdx.x) * 8;
  if (i >= n) return;
  float4 a = *(const float4*)&in[i];
  float4 b = *(const float4*)&in[i + 4];
  bf16x8 v;
  v[0] = (__bf16)a.x; v[1] = (__bf16)a.y; v[2] = (__bf16)a.z; v[3] = (__bf16)a.w;
  v[4] = (__bf16)b.x; v[5] = (__bf16)b.y; v[6] = (__bf16)b.z; v[7] = (__bf16)b.w;
  *(bf16x8*)&out[i] = v;
}

// ---------------------------------------------------------------------------
// Transpose: in [R][C] fp32 -> out [C][R] bf16. 32x32 tiles, 256 threads.
// ---------------------------------------------------------------------------
__global__ void transpose_f32_bf16(const float* __restrict__ in,
                                   __bf16* __restrict__ out, int R, int C) {
  __shared__ float t[32][33];
  int tx = threadIdx.x & 31, ty = threadIdx.x >> 5;  // 32 x 8
  int x = blockIdx.x * 32 + tx;
  int y0 = blockIdx.y * 32 + ty;
#pragma unroll
  for (int i = 0; i < 4; ++i)
    t[ty + 8 * i][tx] = in[(size_t)(y0 + 8 * i) * C + x];
  __syncthreads();
  int x2 = blockIdx.y * 32 + tx;
#pragma unroll
  for (int i = 0; i < 4; ++i)
    out[(size_t)(blockIdx.x * 32 + ty + 8 * i) * R + x2] = (__bf16)t[tx][ty + 8 * i];
}

// ---------------------------------------------------------------------------
// GEMM: C[M][N] = A[M][K]*Bt[N][K]^T + bias[N]. A,Bt bf16, fp32 accum.
// m97 structure + XOR-swizzled LDS: storage chunk (row r, slot s) holds
// global k-chunk s^(r&7) (permuted at gld16-source, lane-linear LDS dest).
// Fragment reads hit slot cc^(l16&7) -> per-phase conflict-free ds_read_b128.
// ---------------------------------------------------------------------------
#define BN 128
#define BK 64

template <int BMT, typename TC>
__global__ __launch_bounds__(256) void gemm_bt_bias(
    const __bf16* __restrict__ A, const __bf16* __restrict__ Bt,
    const float* __restrict__ bias, TC* __restrict__ Cmat,
    int M, int N, int K) {
  constexpr int NI = BMT / 32;  // A chunks per thread; MFMA row-tiles per wave
  __shared__ __align__(16) __bf16 As[BMT * BK];
  __shared__ __align__(16) __bf16 Bs[BN * BK];
  int tid = threadIdx.x;
  int wave = tid >> 6, lane = tid & 63;
  int l16 = lane & 15, quad = lane >> 4;
  int wm = wave >> 1, wn = wave & 1;
  int m0 = blockIdx.y * BMT, n0 = blockIdx.x * BN;

  f32x4 acc[NI][4];
#pragma unroll
  for (int i = 0; i < NI; ++i)
#pragma unroll
    for (int j = 0; j < 4; ++j) acc[i][j] = (f32x4){0.f, 0.f, 0.f, 0.f};

  int row = tid >> 3;                                // 0..31 (+32*i)
  // swizzled source column: slot (tid&7) of row r fetches chunk (tid&7)^(r&7)
  int kc = ((tid & 7) ^ ((tid >> 3) & 7)) * 8;       // i*32 doesn't change r&7
  // fragment-read xor key (elements): chunk cc -> slot cc^(l16&7)
  int xr = (l16 & 7) * 8;

  for (int k0 = 0; k0 < K; k0 += BK) {
#pragma unroll
    for (int i = 0; i < NI; ++i)
      gld16(&A[(size_t)(m0 + row + i * 32) * K + k0 + kc],
            (char*)As + (i * 256 + wave * 64) * 16);
#pragma unroll
    for (int j = 0; j < 4; ++j)
      gld16(&Bt[(size_t)(n0 + row + j * 32) * K + k0 + kc],
            (char*)Bs + (j * 256 + wave * 64) * 16);
    __syncthreads();
#pragma unroll
    for (int ks = 0; ks < 2; ++ks) {
      bf16x8 af[NI], bfr[4];
#pragma unroll
      for (int i = 0; i < NI; ++i)
        af[i] = *(const bf16x8*)&As[(wm * (BMT / 2) + i * 16 + l16) * BK +
                                    ((ks * 32 + quad * 8) ^ xr)];
#pragma unroll
      for (int j = 0; j < 4; ++j)
        bfr[j] = *(const bf16x8*)&Bs[(wn * 64 + j * 16 + l16) * BK +
                                     ((ks * 32 + quad * 8) ^ xr)];
#pragma unroll
      for (int i = 0; i < NI; ++i)
#pragma unroll
        for (int j = 0; j < 4; ++j) acc[i][j] = MFMA_BF16(af[i], bfr[j], acc[i][j]);
    }
    __syncthreads();
  }
  // epilogue: D row = quad*4+r, col = lane&15 within each 16x16 tile
#pragma unroll
  for (int i = 0; i < NI; ++i) {
#pragma unroll
    for (int j = 0; j < 4; ++j) {
      int col = n0 + wn * 64 + j * 16 + l16;
      float bv = bias[col];
#pragma unroll
      for (int r = 0; r < 4; ++r) {
        int rw = m0 + wm * (BMT / 2) + i * 16 + quad * 4 + r;
        Cmat[(size_t)rw * N + col] = (TC)(acc[i][j][r] + bv);
      }
    }
  }
}

// ---------------------------------------------------------------------------
// Causal flash attention, no-max softmax. qkv [B*T][3C] bf16.
// Q-tile = 128 rows/block, 4 waves x 32 q-rows (2 MFMA row-tiles/wave) so
// K/V fragment reads amortize over 2 row-tiles. Grid (32=bh, 16=y) with
// qt = y<8 ? y : 23-y  =>  co-resident pairs (id, id+256) get qt, 15-qt:
// every CU runs exactly 34 kt-iters across 2 overlapping blocks (the round-8
// regression was 1 block/CU = zero cross-block latency hiding).
// K: unpadded 64-stride, gld16 DMA + source-XOR swizzle (GEMM-proven).
// V: padded-72 transpose scatter with key^d0 swizzle. Double-buffered,
// one barrier per tile.
// ---------------------------------------------------------------------------
__global__ __launch_bounds__(256) void attn_causal(
    const __bf16* __restrict__ qkv, __bf16* __restrict__ y) {
  __shared__ __align__(16) __bf16 Kb[2][64 * 64];   // [key][chunk^(key&7)]
  __shared__ __align__(16) __bf16 Vb[2][64 * 72];   // [dim][key ^ (dim&56)]
  __shared__ __align__(16) __bf16 Ps[4][32 * 72];   // per-wave P [qrow32][key]
  const int tid = threadIdx.x;
  const int wave = tid >> 6, lane = tid & 63;
  const int l16 = lane & 15, quad = lane >> 4;
  const int bh = blockIdx.x;
  const int b = bh >> 4, h = bh & 15;
  const int RS = 3072;
  const int yb = blockIdx.y;
  const int qt = (yb < 8) ? yb : 23 - yb;           // 128-row q-tile index
  const int KT = 2 * qt + 2;                        // 64-key tiles to process

  const int key0 = tid >> 3;                        // 0..31 (+32 for chunk 1)
  const int d0 = (tid & 7) * 8;
  // K source-permuted column (gld16 lane-linear dest): slot s of row r gets
  // global chunk s^(r&7); r&7 == (tid>>3)&7 for both chunk halves.
  const int kcs = ((tid & 7) ^ ((tid >> 3) & 7)) * 8;
  const int xr = (l16 & 7) * 8;                     // frag-read xor key
  const __bf16* kbase = qkv + (size_t)(b * 2048) * RS + 1024 + h * 64 + kcs;
  const __bf16* vbase = qkv + (size_t)(b * 2048) * RS + 2048 + h * 64 + d0;

  // Q fragments for 2 row-tiles: A[m=lane&15][k=quad*8+j]
  bf16x8 qf[2][2];
#pragma unroll
  for (int t = 0; t < 2; ++t) {
    int qrow = b * 2048 + qt * 128 + wave * 32 + t * 16 + l16;
    const __bf16* qbase = qkv + (size_t)qrow * RS + h * 64;
    qf[t][0] = *(const bf16x8*)(qbase + quad * 8);
    qf[t][1] = *(const bf16x8*)(qbase + 32 + quad * 8);
  }

  float l_i[2][4];
  f32x4 o[2][4];
#pragma unroll
  for (int t = 0; t < 2; ++t)
#pragma unroll
    for (int r = 0; r < 4; ++r) l_i[t][r] = 0.f;
#pragma unroll
  for (int t = 0; t < 2; ++t)
#pragma unroll
    for (int j = 0; j < 4; ++j) o[t][j] = (f32x4){0.f, 0.f, 0.f, 0.f};

  // stage tile 0 into buffer 0: K via DMA, V via reg scatter
  bf16x8 vreg[2];
#pragma unroll
  for (int i = 0; i < 2; ++i) {
    gld16(kbase + (size_t)(key0 + 32 * i) * RS,
          (char*)Kb[0] + (i * 256 + wave * 64 + lane) * 16);
    vreg[i] = *(const bf16x8*)(vbase + (size_t)(key0 + 32 * i) * RS);
  }
#pragma unroll
  for (int i = 0; i < 2; ++i) {
    int key = key0 + 32 * i;
#pragma unroll
    for (int jj = 0; jj < 8; ++jj)
      Vb[0][(d0 + jj) * 72 + (key ^ d0)] = vreg[i][jj];
  }
  __syncthreads();

  for (int kt = 0; kt < KT; ++kt) {
    const int cur = kt & 1;
    // prefetch tile kt+1: K DMA into other buffer, V into regs
    if (kt + 1 < KT) {
#pragma unroll
      for (int i = 0; i < 2; ++i) {
        gld16(kbase + (size_t)((kt + 1) * 64 + key0 + 32 * i) * RS,
              (char*)Kb[cur ^ 1] + (i * 256 + wave * 64 + lane) * 16);
        vreg[i] = *(const bf16x8*)(vbase + (size_t)((kt + 1) * 64 + key0 + 32 * i) * RS);
      }
    }

    // S = Q K^T for both row-tiles (K frags read once, used twice)
    f32x4 s[2][4];
#pragma unroll
    for (int t = 0; t < 2; ++t)
#pragma unroll
      for (int j = 0; j < 4; ++j) s[t][j] = (f32x4){0.f, 0.f, 0.f, 0.f};
#pragma unroll
    for (int j = 0; j < 4; ++j) {
      bf16x8 kf0 = *(const bf16x8*)&Kb[cur][(j * 16 + l16) * 64 + ((quad * 8) ^ xr)];
      bf16x8 kf1 = *(const bf16x8*)&Kb[cur][(j * 16 + l16) * 64 + ((32 + quad * 8) ^ xr)];
#pragma unroll
      for (int t = 0; t < 2; ++t) {
        s[t][j] = MFMA_BF16(qf[t][0], kf0, s[t][j]);
        s[t][j] = MFMA_BF16(qf[t][1], kf1, s[t][j]);
      }
    }

    // causal mask on diagonal region (uniform branch)
    if (kt >= 2 * qt) {
      int off = (kt - 2 * qt) * 64;   // key offset within the 128-q block
#pragma unroll
      for (int t = 0; t < 2; ++t) {
        int qg = wave * 32 + t * 16 + quad * 4;  // +r
#pragma unroll
        for (int j = 0; j < 4; ++j)
#pragma unroll
          for (int r = 0; r < 4; ++r)
            if (j * 16 + l16 + off > qg + r) s[t][j][r] = NEG_INF;
      }
    }

    // P = exp2(S*SCL); per-lane l accum; C/D-layout -> LDS (wave-private)
#pragma unroll
    for (int t = 0; t < 2; ++t)
#pragma unroll
      for (int r = 0; r < 4; ++r)
#pragma unroll
        for (int j = 0; j < 4; ++j) {
          float p = __builtin_amdgcn_exp2f(s[t][j][r] * SCL);
          l_i[t][r] += p;
          Ps[wave][(t * 16 + quad * 4 + r) * 72 + j * 16 + l16] = (__bf16)p;
        }

    // O += P V (V frags read once, used for both row-tiles)
#pragma unroll
    for (int ks = 0; ks < 2; ++ks) {
      bf16x8 pf[2];
#pragma unroll
      for (int t = 0; t < 2; ++t)
        pf[t] = *(const bf16x8*)&Ps[wave][(t * 16 + l16) * 72 + ks * 32 + quad * 8];
#pragma unroll
      for (int j = 0; j < 4; ++j) {
        int dim = j * 16 + l16;
        bf16x8 vf = *(const bf16x8*)&Vb[cur][dim * 72 + ((ks * 32 + quad * 8) ^ (dim & 56))];
#pragma unroll
        for (int t = 0; t < 2; ++t) o[t][j] = MFMA_BF16(pf[t], vf, o[t][j]);
      }
    }

    // scatter prefetched V into the other buffer
    if (kt + 1 < KT) {
#pragma unroll
      for (int i = 0; i < 2; ++i) {
        int key = key0 + 32 * i;
#pragma unroll
        for (int jj = 0; jj < 8; ++jj)
          Vb[cur ^ 1][(d0 + jj) * 72 + (key ^ d0)] = vreg[i][jj];
      }
    }
    __syncthreads();  // single barrier per tile (also drains K DMA)
  }

  // reduce l across the 16-lane row group, then normalize + store
#pragma unroll
  for (int t = 0; t < 2; ++t) {
    int orow = b * 2048 + qt * 128 + wave * 32 + t * 16 + quad * 4;
#pragma unroll
    for (int r = 0; r < 4; ++r) {
      float l = l_i[t][r];
      l += __shfl_xor(l, 1);
      l += __shfl_xor(l, 2);
      l += __shfl_xor(l, 4);
      l += __shfl_xor(l, 8);
      float inv = 1.f / l;
#pragma unroll
      for (int j = 0; j < 4; ++j)
        y[(size_t)(orow + r) * 1024 + h * 64 + j * 16 + l16] = (__bf16)(o[t][j][r] * inv);
    }
  }
}

// ---------------------------------------------------------------------------
extern "C" void kernel_launch(void* const* d_in, const int* in_sizes, int n_in,
                              void* d_out, int out_size, void* d_ws, size_t ws_size,
                              hipStream_t stream) {
  (void)in_sizes; (void)n_in; (void)out_size; (void)ws_size;
  const float* x      = (const float*)d_in[0];  // [2,2048,1024] fp32
  const float* w_attn = (const float*)d_in[1];  // [1024,3072]
  const float* b_attn = (const float*)d_in[2];  // [3072]
  const float* w_proj = (const float*)d_in[3];  // [1024,1024]
  const float* b_proj = (const float*)d_in[4];  // [1024]
  float* out = (float*)d_out;                   // [2,2048,1024] fp32

  __bf16* wt_attn = (__bf16*)d_ws;                       // [3072][1024]
  __bf16* wt_proj = wt_attn + (size_t)3072 * 1024;       // [1024][1024]
  __bf16* qkv     = wt_proj + (size_t)1024 * 1024;       // [4096][3072]
  __bf16* ybuf    = qkv + (size_t)4096 * 3072;           // [4096][1024]

  // x -> bf16, staged in ybuf (attention overwrites it later; same stream)
  cast_f32_bf16<<<4096 * 1024 / 2048, 256, 0, stream>>>(x, ybuf, 4096 * 1024);

  transpose_f32_bf16<<<dim3(3072 / 32, 1024 / 32), 256, 0, stream>>>(w_attn, wt_attn, 1024, 3072);
  transpose_f32_bf16<<<dim3(1024 / 32, 1024 / 32), 256, 0, stream>>>(w_proj, wt_proj, 1024, 1024);

  // qkv = x @ w_attn + b_attn   (768 blocks, BM=128)
  gemm_bt_bias<128, __bf16><<<dim3(3072 / BN, 4096 / 128), 256, 0, stream>>>(
      ybuf, wt_attn, b_attn, qkv, 4096, 3072, 1024);

  // y = causal_attention(qkv), overwrites ybuf (512 blocks, q-tile 128)
  attn_causal<<<dim3(2 * 16, 16), 256, 0, stream>>>(qkv, ybuf);

  // out = y @ w_proj + b_proj   (512 blocks, BM=64 for occupancy)
  gemm_bt_bias<64, float><<<dim3(1024 / BN, 4096 / 64), 256, 0, stream>>>(
      ybuf, wt_proj, b_proj, out, 4096, 1024, 1024);
}

// Round 10
// 180.234 us; speedup vs baseline: 1.1302x; 1.0760x over previous
//
#include <hip/hip_runtime.h>

typedef __bf16 bf16x8 __attribute__((ext_vector_type(8)));
typedef __bf16 bf16x4 __attribute__((ext_vector_type(4)));
typedef float  f32x4  __attribute__((ext_vector_type(4)));

#define MFMA_BF16(a, b, c) __builtin_amdgcn_mfma_f32_16x16x32_bf16((a), (b), (c), 0, 0, 0)
#define NEG_INF (-1e30f)
// softmax scale folded with log2(e): exp(s*0.125) == exp2(s*0.125*1.442695)
#define SCL 0.18033688f

__device__ __forceinline__ void gld16(const void* g, void* l) {
  __builtin_amdgcn_global_load_lds(
      (const __attribute__((address_space(1))) void*)g,
      (__attribute__((address_space(3))) void*)l, 16, 0, 0);
}

// ---------------------------------------------------------------------------
// Cast fp32 -> bf16, 8 elems/thread.
// ---------------------------------------------------------------------------
__global__ void cast_f32_bf16(const float* __restrict__ in,
                              __bf16* __restrict__ out, int n) {
  int i = (blockIdx.x * 256 + threadIdx.x) * 8;
  if (i >= n) return;
  float4 a = *(const float4*)&in[i];
  float4 b = *(const float4*)&in[i + 4];
  bf16x8 v;
  v[0] = (__bf16)a.x; v[1] = (__bf16)a.y; v[2] = (__bf16)a.z; v[3] = (__bf16)a.w;
  v[4] = (__bf16)b.x; v[5] = (__bf16)b.y; v[6] = (__bf16)b.z; v[7] = (__bf16)b.w;
  *(bf16x8*)&out[i] = v;
}

// ---------------------------------------------------------------------------
// Transpose: in [R][C] fp32 -> out [C][R] bf16. 32x32 tiles, 256 threads.
// ---------------------------------------------------------------------------
__global__ void transpose_f32_bf16(const float* __restrict__ in,
                                   __bf16* __restrict__ out, int R, int C) {
  __shared__ float t[32][33];
  int tx = threadIdx.x & 31, ty = threadIdx.x >> 5;  // 32 x 8
  int x = blockIdx.x * 32 + tx;
  int y0 = blockIdx.y * 32 + ty;
#pragma unroll
  for (int i = 0; i < 4; ++i)
    t[ty + 8 * i][tx] = in[(size_t)(y0 + 8 * i) * C + x];
  __syncthreads();
  int x2 = blockIdx.y * 32 + tx;
#pragma unroll
  for (int i = 0; i < 4; ++i)
    out[(size_t)(blockIdx.x * 32 + ty + 8 * i) * R + x2] = (__bf16)t[tx][ty + 8 * i];
}

// ---------------------------------------------------------------------------
// GEMM: C[M][N] = A[M][K]*Bt[N][K]^T + bias[N]. A,Bt bf16, fp32 accum.
// m97 structure + XOR-swizzled LDS (source-permuted gld16; conflict-free).
// ---------------------------------------------------------------------------
#define BN 128
#define BK 64

template <int BMT, typename TC>
__global__ __launch_bounds__(256) void gemm_bt_bias(
    const __bf16* __restrict__ A, const __bf16* __restrict__ Bt,
    const float* __restrict__ bias, TC* __restrict__ Cmat,
    int M, int N, int K) {
  constexpr int NI = BMT / 32;  // A chunks per thread; MFMA row-tiles per wave
  __shared__ __align__(16) __bf16 As[BMT * BK];
  __shared__ __align__(16) __bf16 Bs[BN * BK];
  int tid = threadIdx.x;
  int wave = tid >> 6, lane = tid & 63;
  int l16 = lane & 15, quad = lane >> 4;
  int wm = wave >> 1, wn = wave & 1;
  int m0 = blockIdx.y * BMT, n0 = blockIdx.x * BN;

  f32x4 acc[NI][4];
#pragma unroll
  for (int i = 0; i < NI; ++i)
#pragma unroll
    for (int j = 0; j < 4; ++j) acc[i][j] = (f32x4){0.f, 0.f, 0.f, 0.f};

  int row = tid >> 3;                                // 0..31 (+32*i)
  // swizzled source column: slot (tid&7) of row r fetches chunk (tid&7)^(r&7)
  int kc = ((tid & 7) ^ ((tid >> 3) & 7)) * 8;       // i*32 doesn't change r&7
  // fragment-read xor key (elements): chunk cc -> slot cc^(l16&7)
  int xr = (l16 & 7) * 8;

  for (int k0 = 0; k0 < K; k0 += BK) {
#pragma unroll
    for (int i = 0; i < NI; ++i)
      gld16(&A[(size_t)(m0 + row + i * 32) * K + k0 + kc],
            (char*)As + (i * 256 + wave * 64) * 16);
#pragma unroll
    for (int j = 0; j < 4; ++j)
      gld16(&Bt[(size_t)(n0 + row + j * 32) * K + k0 + kc],
            (char*)Bs + (j * 256 + wave * 64) * 16);
    __syncthreads();
#pragma unroll
    for (int ks = 0; ks < 2; ++ks) {
      bf16x8 af[NI], bfr[4];
#pragma unroll
      for (int i = 0; i < NI; ++i)
        af[i] = *(const bf16x8*)&As[(wm * (BMT / 2) + i * 16 + l16) * BK +
                                    ((ks * 32 + quad * 8) ^ xr)];
#pragma unroll
      for (int j = 0; j < 4; ++j)
        bfr[j] = *(const bf16x8*)&Bs[(wn * 64 + j * 16 + l16) * BK +
                                     ((ks * 32 + quad * 8) ^ xr)];
#pragma unroll
      for (int i = 0; i < NI; ++i)
#pragma unroll
        for (int j = 0; j < 4; ++j) acc[i][j] = MFMA_BF16(af[i], bfr[j], acc[i][j]);
    }
    __syncthreads();
  }
  // epilogue: D row = quad*4+r, col = lane&15 within each 16x16 tile
#pragma unroll
  for (int i = 0; i < NI; ++i) {
#pragma unroll
    for (int j = 0; j < 4; ++j) {
      int col = n0 + wn * 64 + j * 16 + l16;
      float bv = bias[col];
#pragma unroll
      for (int r = 0; r < 4; ++r) {
        int rw = m0 + wm * (BMT / 2) + i * 16 + quad * 4 + r;
        Cmat[(size_t)rw * N + col] = (TC)(acc[i][j][r] + bv);
      }
    }
  }
}

// ---------------------------------------------------------------------------
// Causal flash attention, no-max softmax, S^T formulation. qkv [B*T][3C] bf16.
// Grid (32=bh, 16=pair): block does qt=pair then 31-pair => uniform 33 iters,
// 512 blocks = 2/CU for the whole duration (round-9's unequal-duration pairing
// collapsed to 1 block/CU mid-flight).
// S^T = K Q^T via MFMA(kf, qf): lane then holds P^T[key=quad*4+r][qrow=l16],
// so P stores to Ps[qrow][key] are 4-element contiguous b64 writes (vs 32
// scalar b16 in the S formulation), and l_i is a single scalar per lane.
// K: unpadded 64-stride via gld16 DMA + source-XOR swizzle (GEMM-proven).
// V: padded-72 transpose scatter with key^d0 swizzle. Double-buffered,
// one barrier per tile.
// ---------------------------------------------------------------------------
__global__ __launch_bounds__(256) void attn_causal(
    const __bf16* __restrict__ qkv, __bf16* __restrict__ y) {
  __shared__ __align__(16) __bf16 Kb[2][64 * 64];   // [key][chunk^(key&7)]
  __shared__ __align__(16) __bf16 Vb[2][64 * 72];   // [dim][key ^ (dim&56)]
  __shared__ __align__(16) __bf16 Ps[4][16 * 72];   // per-wave P [qrow16][key]
  const int tid = threadIdx.x;
  const int wave = tid >> 6, lane = tid & 63;
  const int l16 = lane & 15, quad = lane >> 4;
  const int bh = blockIdx.x;
  const int b = bh >> 4, h = bh & 15;
  const int RS = 3072;

  const int key0 = tid >> 3;                        // 0..31 (+32 for chunk 1)
  const int d0 = (tid & 7) * 8;
  const int kcs = ((tid & 7) ^ ((tid >> 3) & 7)) * 8;  // K source-permuted col
  const int xr = (l16 & 7) * 8;                     // frag-read xor key
  const __bf16* kbase = qkv + (size_t)(b * 2048) * RS + 1024 + h * 64 + kcs;
  const __bf16* vbase = qkv + (size_t)(b * 2048) * RS + 2048 + h * 64 + d0;

#pragma unroll 1
  for (int phase = 0; phase < 2; ++phase) {
    const int qt = phase ? (31 - (int)blockIdx.y) : (int)blockIdx.y;

    // Q fragment: dual-use A/B layout [free=l16][k=quad*8+j]
    int qrow = b * 2048 + qt * 64 + wave * 16 + l16;
    const __bf16* qbase = qkv + (size_t)qrow * RS + h * 64;
    bf16x8 qf0 = *(const bf16x8*)(qbase + quad * 8);
    bf16x8 qf1 = *(const bf16x8*)(qbase + 32 + quad * 8);

    float l_i = 0.f;
    f32x4 o[4];
#pragma unroll
    for (int j = 0; j < 4; ++j) o[j] = (f32x4){0.f, 0.f, 0.f, 0.f};

    // stage tile 0 into buffer 0: K via DMA, V via reg scatter
    bf16x8 vreg[2];
#pragma unroll
    for (int i = 0; i < 2; ++i) {
      gld16(kbase + (size_t)(key0 + 32 * i) * RS,
            (char*)Kb[0] + (i * 256 + tid) * 16);
      vreg[i] = *(const bf16x8*)(vbase + (size_t)(key0 + 32 * i) * RS);
    }
#pragma unroll
    for (int i = 0; i < 2; ++i) {
      int key = key0 + 32 * i;
#pragma unroll
      for (int jj = 0; jj < 8; ++jj)
        Vb[0][(d0 + jj) * 72 + (key ^ d0)] = vreg[i][jj];
    }
    __syncthreads();

    for (int kt = 0; kt <= qt; ++kt) {
      const int cur = kt & 1;
      // prefetch tile kt+1: K DMA into other buffer, V into regs
      if (kt < qt) {
#pragma unroll
        for (int i = 0; i < 2; ++i) {
          gld16(kbase + (size_t)((kt + 1) * 64 + key0 + 32 * i) * RS,
                (char*)Kb[cur ^ 1] + (i * 256 + tid) * 16);
          vreg[i] = *(const bf16x8*)(vbase + (size_t)((kt + 1) * 64 + key0 + 32 * i) * RS);
        }
      }

      // S^T = K Q^T : lane holds S^T[key=j*16+quad*4+r][qrow=wave*16+l16]
      f32x4 s[4];
#pragma unroll
      for (int j = 0; j < 4; ++j) s[j] = (f32x4){0.f, 0.f, 0.f, 0.f};
#pragma unroll
      for (int j = 0; j < 4; ++j) {
        bf16x8 kf0 = *(const bf16x8*)&Kb[cur][(j * 16 + l16) * 64 + ((quad * 8) ^ xr)];
        bf16x8 kf1 = *(const bf16x8*)&Kb[cur][(j * 16 + l16) * 64 + ((32 + quad * 8) ^ xr)];
        s[j] = MFMA_BF16(kf0, qf0, s[j]);
        s[j] = MFMA_BF16(kf1, qf1, s[j]);
      }

      // causal mask only on the diagonal tile (uniform branch)
      if (kt == qt) {
        int qg = wave * 16 + l16;
#pragma unroll
        for (int j = 0; j < 4; ++j)
#pragma unroll
          for (int r = 0; r < 4; ++r)
            if (j * 16 + quad * 4 + r > qg) s[j][r] = NEG_INF;
      }

      // P = exp2(S*SCL); scalar l accum (lane owns qrow=l16);
      // P^T reg layout -> contiguous b64 stores to Ps[qrow][key]
#pragma unroll
      for (int j = 0; j < 4; ++j) {
        bf16x4 pb;
#pragma unroll
        for (int r = 0; r < 4; ++r) {
          float p = __builtin_amdgcn_exp2f(s[j][r] * SCL);
          l_i += p;
          pb[r] = (__bf16)p;
        }
        *(bf16x4*)&Ps[wave][l16 * 72 + j * 16 + quad * 4] = pb;
      }

      // O += P V : A=P[qrow][key] from Ps (b128), B=V[key][dim] from Vb
#pragma unroll
      for (int ks = 0; ks < 2; ++ks) {
        bf16x8 pf = *(const bf16x8*)&Ps[wave][l16 * 72 + ks * 32 + quad * 8];
#pragma unroll
        for (int j = 0; j < 4; ++j) {
          int dim = j * 16 + l16;
          bf16x8 vf = *(const bf16x8*)&Vb[cur][dim * 72 + ((ks * 32 + quad * 8) ^ (dim & 56))];
          o[j] = MFMA_BF16(pf, vf, o[j]);
        }
      }

      // scatter prefetched V into the other buffer
      if (kt < qt) {
#pragma unroll
        for (int i = 0; i < 2; ++i) {
          int key = key0 + 32 * i;
#pragma unroll
          for (int jj = 0; jj < 8; ++jj)
            Vb[cur ^ 1][(d0 + jj) * 72 + (key ^ d0)] = vreg[i][jj];
        }
      }
      __syncthreads();  // single barrier per tile (also drains K DMA)
    }

    // l lives at lane l16 (all quads identical after xor-16/32 reduction)
    float lred = l_i;
    lred += __shfl_xor(lred, 16);
    lred += __shfl_xor(lred, 32);
    int orow = b * 2048 + qt * 64 + wave * 16 + quad * 4;
#pragma unroll
    for (int r = 0; r < 4; ++r) {
      float inv = 1.f / __shfl(lred, quad * 4 + r);
#pragma unroll
      for (int j = 0; j < 4; ++j)
        y[(size_t)(orow + r) * 1024 + h * 64 + j * 16 + l16] = (__bf16)(o[j][r] * inv);
    }
  }
}

// ---------------------------------------------------------------------------
extern "C" void kernel_launch(void* const* d_in, const int* in_sizes, int n_in,
                              void* d_out, int out_size, void* d_ws, size_t ws_size,
                              hipStream_t stream) {
  (void)in_sizes; (void)n_in; (void)out_size; (void)ws_size;
  const float* x      = (const float*)d_in[0];  // [2,2048,1024] fp32
  const float* w_attn = (const float*)d_in[1];  // [1024,3072]
  const float* b_attn = (const float*)d_in[2];  // [3072]
  const float* w_proj = (const float*)d_in[3];  // [1024,1024]
  const float* b_proj = (const float*)d_in[4];  // [1024]
  float* out = (float*)d_out;                   // [2,2048,1024] fp32

  __bf16* wt_attn = (__bf16*)d_ws;                       // [3072][1024]
  __bf16* wt_proj = wt_attn + (size_t)3072 * 1024;       // [1024][1024]
  __bf16* qkv     = wt_proj + (size_t)1024 * 1024;       // [4096][3072]
  __bf16* ybuf    = qkv + (size_t)4096 * 3072;           // [4096][1024]

  // x -> bf16, staged in ybuf (attention overwrites it later; same stream)
  cast_f32_bf16<<<4096 * 1024 / 2048, 256, 0, stream>>>(x, ybuf, 4096 * 1024);

  transpose_f32_bf16<<<dim3(3072 / 32, 1024 / 32), 256, 0, stream>>>(w_attn, wt_attn, 1024, 3072);
  transpose_f32_bf16<<<dim3(1024 / 32, 1024 / 32), 256, 0, stream>>>(w_proj, wt_proj, 1024, 1024);

  // qkv = x @ w_attn + b_attn   (768 blocks, BM=128)
  gemm_bt_bias<128, __bf16><<<dim3(3072 / BN, 4096 / 128), 256, 0, stream>>>(
      ybuf, wt_attn, b_attn, qkv, 4096, 3072, 1024);

  // y = causal_attention(qkv), overwrites ybuf (512 blocks, uniform 33 iters)
  attn_causal<<<dim3(2 * 16, 16), 256, 0, stream>>>(qkv, ybuf);

  // out = y @ w_proj + b_proj   (512 blocks, BM=64 for occupancy)
  gemm_bt_bias<64, float><<<dim3(1024 / BN, 4096 / 64), 256, 0, stream>>>(
      ybuf, wt_proj, b_proj, out, 4096, 1024, 1024);
}

// Round 11
// 179.538 us; speedup vs baseline: 1.1346x; 1.0039x over previous
//
#include <hip/hip_runtime.h>

typedef __bf16 bf16x8 __attribute__((ext_vector_type(8)));
typedef __bf16 bf16x4 __attribute__((ext_vector_type(4)));
typedef float  f32x4  __attribute__((ext_vector_type(4)));

#define MFMA_BF16(a, b, c) __builtin_amdgcn_mfma_f32_16x16x32_bf16((a), (b), (c), 0, 0, 0)
#define NEG_INF (-1e30f)
// softmax scale folded with log2(e): exp(s*0.125) == exp2(s*0.125*1.442695)
#define SCL 0.18033688f

__device__ __forceinline__ void gld16(const void* g, void* l) {
  __builtin_amdgcn_global_load_lds(
      (const __attribute__((address_space(1))) void*)g,
      (__attribute__((address_space(3))) void*)l, 16, 0, 0);
}

// ---------------------------------------------------------------------------
// Cast fp32 -> bf16, 8 elems/thread.
// ---------------------------------------------------------------------------
__global__ void cast_f32_bf16(const float* __restrict__ in,
                              __bf16* __restrict__ out, int n) {
  int i = (blockIdx.x * 256 + threadIdx.x) * 8;
  if (i >= n) return;
  float4 a = *(const float4*)&in[i];
  float4 b = *(const float4*)&in[i + 4];
  bf16x8 v;
  v[0] = (__bf16)a.x; v[1] = (__bf16)a.y; v[2] = (__bf16)a.z; v[3] = (__bf16)a.w;
  v[4] = (__bf16)b.x; v[5] = (__bf16)b.y; v[6] = (__bf16)b.z; v[7] = (__bf16)b.w;
  *(bf16x8*)&out[i] = v;
}

// ---------------------------------------------------------------------------
// Transpose: in [R][C] fp32 -> out [C][R] bf16. 32x32 tiles, 256 threads.
// ---------------------------------------------------------------------------
__global__ void transpose_f32_bf16(const float* __restrict__ in,
                                   __bf16* __restrict__ out, int R, int C) {
  __shared__ float t[32][33];
  int tx = threadIdx.x & 31, ty = threadIdx.x >> 5;  // 32 x 8
  int x = blockIdx.x * 32 + tx;
  int y0 = blockIdx.y * 32 + ty;
#pragma unroll
  for (int i = 0; i < 4; ++i)
    t[ty + 8 * i][tx] = in[(size_t)(y0 + 8 * i) * C + x];
  __syncthreads();
  int x2 = blockIdx.y * 32 + tx;
#pragma unroll
  for (int i = 0; i < 4; ++i)
    out[(size_t)(blockIdx.x * 32 + ty + 8 * i) * R + x2] = (__bf16)t[tx][ty + 8 * i];
}

// ---------------------------------------------------------------------------
// V transpose: qkv V-region (b, t, h, d) -> vt[(b*16+h)*64 + d][t], bf16.
// Grid (64 t-tiles, 2 d-tiles, 32 bh), 256 threads, 32x32 tiles.
// ---------------------------------------------------------------------------
__global__ void transpose_v(const __bf16* __restrict__ qkv,
                            __bf16* __restrict__ vt) {
  __shared__ __bf16 t[32][33];
  int tx = threadIdx.x & 31, ty = threadIdx.x >> 5;  // 32 x 8
  int bh = blockIdx.z, b = bh >> 4, h = bh & 15;
  int t0 = blockIdx.x * 32, d0 = blockIdx.y * 32;
#pragma unroll
  for (int i = 0; i < 4; ++i)
    t[ty + 8 * i][tx] =
        qkv[(size_t)(b * 2048 + t0 + ty + 8 * i) * 3072 + 2048 + h * 64 + d0 + tx];
  __syncthreads();
#pragma unroll
  for (int i = 0; i < 4; ++i)
    vt[(size_t)(bh * 64 + d0 + ty + 8 * i) * 2048 + t0 + tx] = t[tx][ty + 8 * i];
}

// ---------------------------------------------------------------------------
// GEMM: C[M][N] = A[M][K]*Bt[N][K]^T + bias[N]. A,Bt bf16, fp32 accum.
// m97 structure + XOR-swizzled LDS (source-permuted gld16; conflict-free).
// ---------------------------------------------------------------------------
#define BN 128
#define BK 64

template <int BMT, typename TC>
__global__ __launch_bounds__(256) void gemm_bt_bias(
    const __bf16* __restrict__ A, const __bf16* __restrict__ Bt,
    const float* __restrict__ bias, TC* __restrict__ Cmat,
    int M, int N, int K) {
  constexpr int NI = BMT / 32;  // A chunks per thread; MFMA row-tiles per wave
  __shared__ __align__(16) __bf16 As[BMT * BK];
  __shared__ __align__(16) __bf16 Bs[BN * BK];
  int tid = threadIdx.x;
  int wave = tid >> 6, lane = tid & 63;
  int l16 = lane & 15, quad = lane >> 4;
  int wm = wave >> 1, wn = wave & 1;
  int m0 = blockIdx.y * BMT, n0 = blockIdx.x * BN;

  f32x4 acc[NI][4];
#pragma unroll
  for (int i = 0; i < NI; ++i)
#pragma unroll
    for (int j = 0; j < 4; ++j) acc[i][j] = (f32x4){0.f, 0.f, 0.f, 0.f};

  int row = tid >> 3;                                // 0..31 (+32*i)
  // swizzled source column: slot (tid&7) of row r fetches chunk (tid&7)^(r&7)
  int kc = ((tid & 7) ^ ((tid >> 3) & 7)) * 8;       // i*32 doesn't change r&7
  // fragment-read xor key (elements): chunk cc -> slot cc^(l16&7)
  int xr = (l16 & 7) * 8;

  for (int k0 = 0; k0 < K; k0 += BK) {
#pragma unroll
    for (int i = 0; i < NI; ++i)
      gld16(&A[(size_t)(m0 + row + i * 32) * K + k0 + kc],
            (char*)As + (i * 256 + wave * 64) * 16);
#pragma unroll
    for (int j = 0; j < 4; ++j)
      gld16(&Bt[(size_t)(n0 + row + j * 32) * K + k0 + kc],
            (char*)Bs + (j * 256 + wave * 64) * 16);
    __syncthreads();
#pragma unroll
    for (int ks = 0; ks < 2; ++ks) {
      bf16x8 af[NI], bfr[4];
#pragma unroll
      for (int i = 0; i < NI; ++i)
        af[i] = *(const bf16x8*)&As[(wm * (BMT / 2) + i * 16 + l16) * BK +
                                    ((ks * 32 + quad * 8) ^ xr)];
#pragma unroll
      for (int j = 0; j < 4; ++j)
        bfr[j] = *(const bf16x8*)&Bs[(wn * 64 + j * 16 + l16) * BK +
                                     ((ks * 32 + quad * 8) ^ xr)];
#pragma unroll
      for (int i = 0; i < NI; ++i)
#pragma unroll
        for (int j = 0; j < 4; ++j) acc[i][j] = MFMA_BF16(af[i], bfr[j], acc[i][j]);
    }
    __syncthreads();
  }
  // epilogue: D row = quad*4+r, col = lane&15 within each 16x16 tile
#pragma unroll
  for (int i = 0; i < NI; ++i) {
#pragma unroll
    for (int j = 0; j < 4; ++j) {
      int col = n0 + wn * 64 + j * 16 + l16;
      float bv = bias[col];
#pragma unroll
      for (int r = 0; r < 4; ++r) {
        int rw = m0 + wm * (BMT / 2) + i * 16 + quad * 4 + r;
        Cmat[(size_t)rw * N + col] = (TC)(acc[i][j][r] + bv);
      }
    }
  }
}

// ---------------------------------------------------------------------------
// Causal flash attention, no-max softmax, S^T formulation. qkv [B*T][3C] bf16,
// vt [bh*64+dim][2048 keys] bf16 (pre-transposed V).
// Grid (32=bh, 16=pair): block does qt=pair then 31-pair => uniform 33 iters,
// 512 blocks = 2/CU for the whole duration.
// Both K and V staged via global_load_lds DMA with source-XOR swizzle
// (round 10 was LDS-pipe-bound; the in-kernel V transpose scatter was ~30%
// of LDS issue). S^T = K Q^T -> P^T regs -> b64 Ps stores; single barrier.
// ---------------------------------------------------------------------------
__global__ __launch_bounds__(256) void attn_causal(
    const __bf16* __restrict__ qkv, const __bf16* __restrict__ vt,
    __bf16* __restrict__ y) {
  __shared__ __align__(16) __bf16 Kb[2][64 * 64];   // [key][dimchunk^(key&7)]
  __shared__ __align__(16) __bf16 Vb[2][64 * 64];   // [dim][keychunk^(dim&7)]
  __shared__ __align__(16) __bf16 Ps[4][16 * 72];   // per-wave P [qrow16][key]
  const int tid = threadIdx.x;
  const int wave = tid >> 6, lane = tid & 63;
  const int l16 = lane & 15, quad = lane >> 4;
  const int bh = blockIdx.x;
  const int b = bh >> 4, h = bh & 15;
  const int RS = 3072;

  const int row0 = tid >> 3;                        // 0..31 (+32 for chunk 1)
  const int kcs = ((tid & 7) ^ ((tid >> 3) & 7)) * 8;  // source-permuted col
  const int xr = (l16 & 7) * 8;                     // frag-read xor key
  const __bf16* kbase = qkv + (size_t)(b * 2048) * RS + 1024 + h * 64 + kcs;
  const __bf16* vbase = vt + (size_t)(bh * 64) * 2048 + kcs;

#pragma unroll 1
  for (int phase = 0; phase < 2; ++phase) {
    const int qt = phase ? (31 - (int)blockIdx.y) : (int)blockIdx.y;

    // Q fragment: dual-use A/B layout [free=l16][k=quad*8+j]
    int qrow = b * 2048 + qt * 64 + wave * 16 + l16;
    const __bf16* qbase = qkv + (size_t)qrow * RS + h * 64;
    bf16x8 qf0 = *(const bf16x8*)(qbase + quad * 8);
    bf16x8 qf1 = *(const bf16x8*)(qbase + 32 + quad * 8);

    float l_i = 0.f;
    f32x4 o[4];
#pragma unroll
    for (int j = 0; j < 4; ++j) o[j] = (f32x4){0.f, 0.f, 0.f, 0.f};

    // stage tile 0 into buffer 0 (K rows = keys; V rows = dims)
#pragma unroll
    for (int i = 0; i < 2; ++i) {
      gld16(kbase + (size_t)(row0 + 32 * i) * RS,
            (char*)Kb[0] + (i * 256 + tid) * 16);
      gld16(vbase + (size_t)(row0 + 32 * i) * 2048,
            (char*)Vb[0] + (i * 256 + tid) * 16);
    }
    __syncthreads();

    for (int kt = 0; kt <= qt; ++kt) {
      const int cur = kt & 1;
      // prefetch tile kt+1 via DMA into the other buffer
      if (kt < qt) {
#pragma unroll
        for (int i = 0; i < 2; ++i) {
          gld16(kbase + (size_t)((kt + 1) * 64 + row0 + 32 * i) * RS,
                (char*)Kb[cur ^ 1] + (i * 256 + tid) * 16);
          gld16(vbase + (size_t)(row0 + 32 * i) * 2048 + (kt + 1) * 64,
                (char*)Vb[cur ^ 1] + (i * 256 + tid) * 16);
        }
      }

      // S^T = K Q^T : lane holds S^T[key=j*16+quad*4+r][qrow=wave*16+l16]
      f32x4 s[4];
#pragma unroll
      for (int j = 0; j < 4; ++j) s[j] = (f32x4){0.f, 0.f, 0.f, 0.f};
#pragma unroll
      for (int j = 0; j < 4; ++j) {
        bf16x8 kf0 = *(const bf16x8*)&Kb[cur][(j * 16 + l16) * 64 + ((quad * 8) ^ xr)];
        bf16x8 kf1 = *(const bf16x8*)&Kb[cur][(j * 16 + l16) * 64 + ((32 + quad * 8) ^ xr)];
        s[j] = MFMA_BF16(kf0, qf0, s[j]);
        s[j] = MFMA_BF16(kf1, qf1, s[j]);
      }

      // causal mask only on the diagonal tile (uniform branch)
      if (kt == qt) {
        int qg = wave * 16 + l16;
#pragma unroll
        for (int j = 0; j < 4; ++j)
#pragma unroll
          for (int r = 0; r < 4; ++r)
            if (j * 16 + quad * 4 + r > qg) s[j][r] = NEG_INF;
      }

      // P = exp2(S*SCL); scalar l accum (lane owns qrow=l16);
      // P^T reg layout -> contiguous b64 stores to Ps[qrow][key]
#pragma unroll
      for (int j = 0; j < 4; ++j) {
        bf16x4 pb;
#pragma unroll
        for (int r = 0; r < 4; ++r) {
          float p = __builtin_amdgcn_exp2f(s[j][r] * SCL);
          l_i += p;
          pb[r] = (__bf16)p;
        }
        *(bf16x4*)&Ps[wave][l16 * 72 + j * 16 + quad * 4] = pb;
      }

      // O += P V : A=P[qrow][key] from Ps (b128), B=V[dim][key] from Vb
#pragma unroll
      for (int ks = 0; ks < 2; ++ks) {
        bf16x8 pf = *(const bf16x8*)&Ps[wave][l16 * 72 + ks * 32 + quad * 8];
#pragma unroll
        for (int j = 0; j < 4; ++j) {
          bf16x8 vf = *(const bf16x8*)&Vb[cur][(j * 16 + l16) * 64 +
                                              ((ks * 32 + quad * 8) ^ xr)];
          o[j] = MFMA_BF16(pf, vf, o[j]);
        }
      }
      __syncthreads();  // single barrier per tile (drains DMA + Ps reads)
    }

    // l lives at lane l16 (all quads identical after xor-16/32 reduction)
    float lred = l_i;
    lred += __shfl_xor(lred, 16);
    lred += __shfl_xor(lred, 32);
    int orow = b * 2048 + qt * 64 + wave * 16 + quad * 4;
#pragma unroll
    for (int r = 0; r < 4; ++r) {
      float inv = 1.f / __shfl(lred, quad * 4 + r);
#pragma unroll
      for (int j = 0; j < 4; ++j)
        y[(size_t)(orow + r) * 1024 + h * 64 + j * 16 + l16] = (__bf16)(o[j][r] * inv);
    }
  }
}

// ---------------------------------------------------------------------------
extern "C" void kernel_launch(void* const* d_in, const int* in_sizes, int n_in,
                              void* d_out, int out_size, void* d_ws, size_t ws_size,
                              hipStream_t stream) {
  (void)in_sizes; (void)n_in; (void)out_size; (void)ws_size;
  const float* x      = (const float*)d_in[0];  // [2,2048,1024] fp32
  const float* w_attn = (const float*)d_in[1];  // [1024,3072]
  const float* b_attn = (const float*)d_in[2];  // [3072]
  const float* w_proj = (const float*)d_in[3];  // [1024,1024]
  const float* b_proj = (const float*)d_in[4];  // [1024]
  float* out = (float*)d_out;                   // [2,2048,1024] fp32

  __bf16* wt_attn = (__bf16*)d_ws;                       // [3072][1024]
  __bf16* wt_proj = wt_attn + (size_t)3072 * 1024;       // [1024][1024]
  __bf16* qkv     = wt_proj + (size_t)1024 * 1024;       // [4096][3072]
  __bf16* ybuf    = qkv + (size_t)4096 * 3072;           // [4096][1024]
  __bf16* vtbuf   = ybuf + (size_t)4096 * 1024;          // [32*64][2048]

  // x -> bf16, staged in ybuf (attention overwrites it later; same stream)
  cast_f32_bf16<<<4096 * 1024 / 2048, 256, 0, stream>>>(x, ybuf, 4096 * 1024);

  transpose_f32_bf16<<<dim3(3072 / 32, 1024 / 32), 256, 0, stream>>>(w_attn, wt_attn, 1024, 3072);
  transpose_f32_bf16<<<dim3(1024 / 32, 1024 / 32), 256, 0, stream>>>(w_proj, wt_proj, 1024, 1024);

  // qkv = x @ w_attn + b_attn   (768 blocks, BM=128)
  gemm_bt_bias<128, __bf16><<<dim3(3072 / BN, 4096 / 128), 256, 0, stream>>>(
      ybuf, wt_attn, b_attn, qkv, 4096, 3072, 1024);

  // V region of qkv -> vt[bh*64+dim][t]
  transpose_v<<<dim3(64, 2, 32), 256, 0, stream>>>(qkv, vtbuf);

  // y = causal_attention(qkv, vt), overwrites ybuf (512 blocks, 33 iters each)
  attn_causal<<<dim3(2 * 16, 16), 256, 0, stream>>>(qkv, vtbuf, ybuf);

  // out = y @ w_proj + b_proj   (512 blocks, BM=64 for occupancy)
  gemm_bt_bias<64, float><<<dim3(1024 / BN, 4096 / 64), 256, 0, stream>>>(
      ybuf, wt_proj, b_proj, out, 4096, 1024, 1024);
}